// Round 10
// baseline (361.586 us; speedup 1.0000x reference)
//
#include <hip/hip_runtime.h>

#define M_DIM 8192
#define N_DIM 6144
#define K_DIM 3072
#define NKT 96            // K / 32 K-tiles
#define NBK (K_DIM / 128) // 24 scale blocks along K

typedef __attribute__((ext_vector_type(8))) short short8;
typedef __attribute__((ext_vector_type(4))) float f32x4v;

// round-to-nearest-even f32->bf16, two packed into a u32
__device__ __forceinline__ unsigned int pk2bf(float a, float b) {
  unsigned int ua = __float_as_uint(a);
  unsigned int ub = __float_as_uint(b);
  ua = (ua + 0x7FFFu + ((ua >> 16) & 1u)) >> 16;
  ub = (ub + 0x7FFFu + ((ub >> 16) & 1u)) & 0xFFFF0000u;
  return ua | ub;
}

__global__ void cvt_x(const float* __restrict__ X, uint2* __restrict__ O, int n4) {
  int stride = gridDim.x * blockDim.x;
  for (int i = blockIdx.x * blockDim.x + threadIdx.x; i < n4; i += stride) {
    float4 v = ((const float4*)X)[i];
    O[i] = make_uint2(pk2bf(v.x, v.y), pk2bf(v.z, v.w));
  }
}

__global__ void cvt_w(const float* __restrict__ W, const float* __restrict__ S,
                      uint2* __restrict__ O, int n4) {
  int stride = gridDim.x * blockDim.x;
  for (int i = blockIdx.x * blockDim.x + threadIdx.x; i < n4; i += stride) {
    unsigned int e = (unsigned int)i * 4u;
    unsigned int n = e / K_DIM;
    unsigned int k = e - n * K_DIM;
    float s = S[(n >> 7) * NBK + (k >> 7)];
    float4 v = ((const float4*)W)[i];
    O[i] = make_uint2(pk2bf(v.x * s, v.y * s), pk2bf(v.z * s, v.w * s));
  }
}

__device__ __forceinline__ void gload16(const unsigned short* g, unsigned short* l) {
  __builtin_amdgcn_global_load_lds(
      (const __attribute__((address_space(1))) void*)g,
      (__attribute__((address_space(3))) void*)l, 16, 0, 0);
}

// 256x128 tile, 4 waves (2Mx2N, wave tile 128x64 — SAME as R5), BK=32,
// ring-3 LDS slots (72 KB) -> TWO blocks/CU (8 waves/CU in two independent
// barrier domains: one block's vmcnt+barrier bubble overlaps the other's
// MFMA stream). Body schedule is R5's proven fixed point: per K32 tile
// {counted vmcnt(6) + barrier; stage t+2 (slot (t-1)%3, read last body);
// 12 ds_read; 32 MFMA under setprio}. Loop unrolled x3 so ring-3 slot
// indices are literals. Quad-local XOR swizzle (R5, conflict-free):
// chunk q stored at q ^ ((row>>1)&3) within each 64B row.
// NOTE: ~236 unified VGPR+AGPR/wave -> exactly 2 waves/SIMD; launch_bounds
// min-waves MUST stay <=2 (R8: forcing 4 spilled acc -> 4 ms).
__global__ __launch_bounds__(256, 2) void gemm_ring3(
    const unsigned short* __restrict__ Xb, const unsigned short* __restrict__ Wb,
    float* __restrict__ Y) {
  extern __shared__ unsigned short lds[];   // A 3x16KB ++ B 3x8KB = 72 KB
  unsigned short* As = lds;                 // slot s @ As + s*8192 (shorts)
  unsigned short* Bs = lds + 24576;         // slot s @ Bs + s*4096

  // XCD-aware mapping: 1536 blocks = 8 XCD x 192; XCD owns 4 bm x 48 bn
  int bid = blockIdx.x;
  int c = bid & 7;
  int j = bid >> 3;                 // 0..191
  int bm = c * 4 + (j / 48);        // 0..31  (M/256)
  int bn = j % 48;                  // 0..47  (N/128)

  int tid = threadIdx.x;
  int lane = tid & 63;
  int wr = (tid >> 6) >> 1;         // 0..1  (wave M row, 128 each)
  int wc = (tid >> 6) & 1;          // 0..1  (wave N col, 64 each)

  // staging: thread t covers rows (t>>2)+{0,64,128,192} (A) / +{0,64} (B),
  // 16B chunk (t&3)^((t>>3)&3) of the row's 64B K-slice (= chunk xor (row>>1)&3)
  int s_row = tid >> 2;                        // 0..63
  int s_q   = (tid & 3) ^ ((tid >> 3) & 3);    // swizzled source chunk
  const unsigned short* Xg = Xb + ((size_t)bm * 256 + s_row) * K_DIM + s_q * 8;
  const unsigned short* Wg = Wb + ((size_t)bn * 128 + s_row) * K_DIM + s_q * 8;

  // fragment read bases: row = lane&15 (+16 per frag), stored chunk
  // (lane>>4)^((lane>>1)&3); row offsets are multiples of 16 so the
  // swizzle class is lane-only (verified R5 derivation).
  int fr = lane & 15;
  int fq = (lane >> 4) ^ ((lane >> 1) & 3);
  const unsigned short* Ab = As + ((wr * 128 + fr) << 5) + (fq << 3);
  const unsigned short* Bb = Bs + ((wc * 64 + fr) << 5) + (fq << 3);

#define STAGE(t, SLOT) {                                                        \
    const unsigned short* _xp = Xg + (size_t)(t) * 32;                          \
    const unsigned short* _wp = Wg + (size_t)(t) * 32;                          \
    unsigned short* _la = As + (SLOT) * 8192 + tid * 8;                         \
    unsigned short* _lb = Bs + (SLOT) * 4096 + tid * 8;                         \
    gload16(_xp,                        _la);                                   \
    gload16(_xp + (size_t) 64 * K_DIM,  _la + 2048);                            \
    gload16(_xp + (size_t)128 * K_DIM,  _la + 4096);                            \
    gload16(_xp + (size_t)192 * K_DIM,  _la + 6144);                            \
    gload16(_wp,                        _lb);                                   \
    gload16(_wp + (size_t) 64 * K_DIM,  _lb + 2048); }

  f32x4v acc[8][4];
#pragma unroll
  for (int m = 0; m < 8; ++m)
#pragma unroll
    for (int n = 0; n < 4; ++n) acc[m][n] = (f32x4v)0.0f;

  STAGE(0, 0); STAGE(1, 1);   // 12 loads in flight

  // BODY: wait own tile (counted: next tile's 6 stay in flight), barrier
  // (stage slot's previous readers done), stage t+2, 12 ds_read, 32 MFMA.
#define BODY(SLOT, STT, STSLOT, DOSTAGE, VM) {                                  \
    if (VM == 6) { asm volatile("s_waitcnt vmcnt(6)\n\ts_barrier" ::: "memory"); } \
    else         { asm volatile("s_waitcnt vmcnt(0)\n\ts_barrier" ::: "memory"); } \
    if (DOSTAGE) STAGE(STT, STSLOT);                                            \
    const unsigned short* _ab = Ab + (SLOT) * 8192;                             \
    const unsigned short* _bb = Bb + (SLOT) * 4096;                             \
    short8 a[8], b[4];                                                          \
    _Pragma("unroll") for (int n = 0; n < 4; ++n)                               \
      b[n] = *(const short8*)(_bb + n * 512);                                   \
    _Pragma("unroll") for (int m = 0; m < 8; ++m)                               \
      a[m] = *(const short8*)(_ab + m * 512);                                   \
    __builtin_amdgcn_s_setprio(1);                                              \
    _Pragma("unroll") for (int m = 0; m < 8; ++m)                               \
      _Pragma("unroll") for (int n = 0; n < 4; ++n)                             \
        acc[m][n] = __builtin_amdgcn_mfma_f32_16x16x32_bf16(a[m], b[n], acc[m][n], 0, 0, 0); \
    __builtin_amdgcn_s_setprio(0); }

  for (int i = 0; i < 31; ++i) {    // t = 3i,3i+1,3i+2 (<=92), stages t+2 (<=94)
    int t = i * 3;
    BODY(0, t + 2, 2, 1, 6);
    BODY(1, t + 3, 0, 1, 6);
    BODY(2, t + 4, 1, 1, 6);
  }
  BODY(0, 95, 2, 1, 6);   // t=93, stages 95 into slot 2 (read at t=92, done)
  BODY(1, 0, 0, 0, 6);    // t=94 (tile 95's 6 loads stay in flight)
  BODY(2, 0, 0, 0, 0);    // t=95 (drain)
#undef BODY
#undef STAGE

  // C/D layout: ncol = lane&15, mrow = (lane>>4)*4 + reg
  int mrow0 = bm * 256 + wr * 128 + ((lane >> 4) << 2);
  int ncol0 = bn * 128 + wc * 64 + (lane & 15);
#pragma unroll
  for (int m = 0; m < 8; ++m)
#pragma unroll
    for (int n = 0; n < 4; ++n)
#pragma unroll
      for (int r = 0; r < 4; ++r)
        Y[(size_t)(mrow0 + m * 16 + r) * N_DIM + ncol0 + n * 16] = acc[m][n][r];
}

// ================= fallback (R1 kernel) if ws too small =================
#define BM 128
#define BN 128
#define NTN (N_DIM / BN)
#define NK2 (K_DIM / 64)
__global__ __launch_bounds__(256, 2) void dq_gemm(
    const float* __restrict__ X, const float* __restrict__ W,
    const float* __restrict__ S, float* __restrict__ Y) {
  __shared__ unsigned short As[BM * 64];
  __shared__ unsigned short Bs[BN * 64];
  int bid = blockIdx.x;
  int cpx = gridDim.x >> 3;
  int wg = (bid & 7) * cpx + (bid >> 3);
  int bm = wg / NTN, bn = wg - (wg / NTN) * NTN;
  int tid = threadIdx.x, lane = tid & 63, wave = tid >> 6;
  int wm = (wave >> 1) << 6, wn = (wave & 1) << 6;
  const float* Xg = X + (size_t)bm * BM * K_DIM;
  const float* Wg = W + (size_t)bn * BN * K_DIM;
  int r0 = tid >> 4, c4 = tid & 15;
  f32x4v acc[4][4];
#pragma unroll
  for (int i = 0; i < 4; ++i)
#pragma unroll
    for (int jj = 0; jj < 4; ++jj) acc[i][jj] = (f32x4v)0.0f;
  float4 xa[8], xb[8];
#pragma unroll
  for (int i = 0; i < 8; ++i) xa[i] = *(const float4*)(Xg + (size_t)(i * 16 + r0) * K_DIM + c4 * 4);
#pragma unroll
  for (int i = 0; i < 8; ++i) xb[i] = *(const float4*)(Wg + (size_t)(i * 16 + r0) * K_DIM + c4 * 4);
  char* Ac = (char*)As; char* Bc = (char*)Bs;
  int sw = (lane & 7) << 4, kb = (lane >> 4) << 4;
  int rA = wm + (lane & 15), rB = wn + (lane & 15);
  for (int kk = 0; kk < NK2; ++kk) {
    float s = S[bn * NBK + (kk >> 1)];
    __syncthreads();
#pragma unroll
    for (int i = 0; i < 8; ++i) {
      int row = i * 16 + r0;
      int off = row * 128 + ((c4 * 8) ^ ((row & 7) << 4));
      *(uint2*)(Ac + off) = make_uint2(pk2bf(xa[i].x, xa[i].y), pk2bf(xa[i].z, xa[i].w));
      *(uint2*)(Bc + off) = make_uint2(pk2bf(xb[i].x * s, xb[i].y * s), pk2bf(xb[i].z * s, xb[i].w * s));
    }
    __syncthreads();
    if (kk + 1 < NK2) {
      const float* Xn = Xg + (size_t)(kk + 1) * 64;
      const float* Wn = Wg + (size_t)(kk + 1) * 64;
#pragma unroll
      for (int i = 0; i < 8; ++i) xa[i] = *(const float4*)(Xn + (size_t)(i * 16 + r0) * K_DIM + c4 * 4);
#pragma unroll
      for (int i = 0; i < 8; ++i) xb[i] = *(const float4*)(Wn + (size_t)(i * 16 + r0) * K_DIM + c4 * 4);
    }
    short8 a0[4], a1[4], b0[4], b1[4];
#pragma unroll
    for (int i = 0; i < 4; ++i) {
      int rowA = rA + i * 16, rowB = rB + i * 16;
      a0[i] = *(const short8*)(Ac + rowA * 128 + (kb ^ sw));
      a1[i] = *(const short8*)(Ac + rowA * 128 + ((kb + 64) ^ sw));
      b0[i] = *(const short8*)(Bc + rowB * 128 + (kb ^ sw));
      b1[i] = *(const short8*)(Bc + rowB * 128 + ((kb + 64) ^ sw));
    }
#pragma unroll
    for (int i = 0; i < 4; ++i)
#pragma unroll
      for (int jj = 0; jj < 4; ++jj) {
        acc[i][jj] = __builtin_amdgcn_mfma_f32_16x16x32_bf16(a0[i], b0[jj], acc[i][jj], 0, 0, 0);
        acc[i][jj] = __builtin_amdgcn_mfma_f32_16x16x32_bf16(a1[i], b1[jj], acc[i][jj], 0, 0, 0);
      }
  }
  int mrow0 = bm * BM + wm + ((lane >> 4) << 2);
  int ncol0 = bn * BN + wn + (lane & 15);
#pragma unroll
  for (int i = 0; i < 4; ++i)
#pragma unroll
    for (int jj = 0; jj < 4; ++jj)
#pragma unroll
      for (int r = 0; r < 4; ++r)
        Y[(size_t)(mrow0 + i * 16 + r) * N_DIM + ncol0 + jj * 16] = acc[i][jj][r];
}

extern "C" void kernel_launch(void* const* d_in, const int* in_sizes, int n_in,
                              void* d_out, int out_size, void* d_ws, size_t ws_size,
                              hipStream_t stream) {
  const float* X = (const float*)d_in[0];
  const float* W = (const float*)d_in[1];
  const float* S = (const float*)d_in[2];
  float* Y = (float*)d_out;

  const size_t xb_bytes = (size_t)M_DIM * K_DIM * 2;
  const size_t wb_bytes = (size_t)N_DIM * K_DIM * 2;
  if (ws_size >= xb_bytes + wb_bytes) {
    unsigned short* Xbf = (unsigned short*)d_ws;
    unsigned short* Wbf = (unsigned short*)((char*)d_ws + xb_bytes);
    cvt_x<<<2048, 256, 0, stream>>>(X, (uint2*)Xbf, M_DIM * K_DIM / 4);
    cvt_w<<<2048, 256, 0, stream>>>(W, S, (uint2*)Wbf, N_DIM * K_DIM / 4);
    static int attr_set = 0;
    if (!attr_set) {
      hipFuncSetAttribute((const void*)gemm_ring3,
                          hipFuncAttributeMaxDynamicSharedMemorySize, 73728);
      attr_set = 1;
    }
    dim3 grid((M_DIM / 256) * (N_DIM / 128));  // 32 * 48 = 1536
    gemm_ring3<<<grid, 256, 73728, stream>>>(Xbf, Wbf, Y);
  } else {
    dim3 grid((M_DIM / BM) * (N_DIM / BN));
    dq_gemm<<<grid, 256, 0, stream>>>(X, W, S, Y);
  }
}

// Round 11
// 358.947 us; speedup vs baseline: 1.0074x; 1.0074x over previous
//
#include <hip/hip_runtime.h>

#define M_DIM 8192
#define N_DIM 6144
#define K_DIM 3072
#define NKT 96            // K / 32 K-tiles
#define NBK (K_DIM / 128) // 24 scale blocks along K

typedef __attribute__((ext_vector_type(8))) short short8;
typedef __attribute__((ext_vector_type(4))) float f32x4v;

// round-to-nearest-even f32->bf16, two packed into a u32
__device__ __forceinline__ unsigned int pk2bf(float a, float b) {
  unsigned int ua = __float_as_uint(a);
  unsigned int ub = __float_as_uint(b);
  ua = (ua + 0x7FFFu + ((ua >> 16) & 1u)) >> 16;
  ub = (ub + 0x7FFFu + ((ub >> 16) & 1u)) & 0xFFFF0000u;
  return ua | ub;
}

__global__ void cvt_x(const float* __restrict__ X, uint2* __restrict__ O, int n4) {
  int stride = gridDim.x * blockDim.x;
  for (int i = blockIdx.x * blockDim.x + threadIdx.x; i < n4; i += stride) {
    float4 v = ((const float4*)X)[i];
    O[i] = make_uint2(pk2bf(v.x, v.y), pk2bf(v.z, v.w));
  }
}

// W fp32 * scale -> bf16 in FRAGMENT-NATIVE layout:
// 16B unit u (linear) decomposes as lane=u&63, nIdx=(u>>6)&3, wc=(u>>8)&3,
// kt=(u>>10)%96, bn=(u>>10)/96; holds 8 bf16 of row n = bn*256+wc*64+nIdx*16+
// (lane&15), k = kt*32+(lane>>4)*8 .. +7. A wave's B-frag load is then
// base + nIdx*1024 + lane*16 : 64 lanes = 1KB contiguous (one dwordx4/lane).
__global__ void cvt_w(const float* __restrict__ W, const float* __restrict__ S,
                      uint4* __restrict__ O, int n16) {
  int stride = gridDim.x * blockDim.x;
  for (int u = blockIdx.x * blockDim.x + threadIdx.x; u < n16; u += stride) {
    int lane = u & 63;
    int nIdx = (u >> 6) & 3;
    int wc = (u >> 8) & 3;
    int r = u >> 10;
    int kt = r % 96;
    int bn = r / 96;
    int n = bn * 256 + wc * 64 + nIdx * 16 + (lane & 15);
    int k = kt * 32 + (lane >> 4) * 8;
    const float4* p = (const float4*)(W + (size_t)n * K_DIM + k);
    float4 v0 = p[0], v1 = p[1];
    float s = S[(n >> 7) * NBK + (k >> 7)];
    uint4 o;
    o.x = pk2bf(v0.x * s, v0.y * s);
    o.y = pk2bf(v0.z * s, v0.w * s);
    o.z = pk2bf(v1.x * s, v1.y * s);
    o.w = pk2bf(v1.z * s, v1.w * s);
    O[u] = o;
  }
}

__device__ __forceinline__ void gload16(const unsigned short* g, unsigned short* l) {
  __builtin_amdgcn_global_load_lds(
      (const __attribute__((address_space(1))) void*)g,
      (__attribute__((address_space(3))) void*)l, 16, 0, 0);
}

// 256x256 tile, BK=32. A: ring-4 LDS (64 KB), R5's proven schedule
// (counted vmcnt + barrier per tile, stage depth 3, quad-local XOR swizzle).
// B: NO LDS — fragment-native global loads into a register double-buffer
// (1-deep prefetch: body t issues B(t+1), consumes B(t)). Cuts per-tile LDS
// traffic from 96rd+32KBwr to 64rd+16KBwr -> MFMA pipe becomes the binder.
// vmcnt(8) uniform: guarantees own A(t) stage (>=13th-newest) arrived;
// B register loads are compiler-tracked (auto waitcnt before use).
// NOTE: ~250 unified VGPR+AGPR/wave; launch_bounds min-waves must stay 2
// (R8: forcing 4 spilled acc -> 4 ms).
__global__ __launch_bounds__(512, 2) void gemm_breg(
    const unsigned short* __restrict__ Xb, const unsigned short* __restrict__ Wb,
    float* __restrict__ Y) {
  extern __shared__ unsigned short lds[];   // As[4][8192 shorts] = 64 KB
  unsigned short* As = lds;

  // XCD-aware mapping: 768 blocks = 8 XCD x 96; each XCD owns 4 bm x 24 bn
  int bid = blockIdx.x;
  int c = bid & 7;
  int j = bid >> 3;                 // 0..95
  int bm = c * 4 + (j / 24);        // 0..31
  int bn = j % 24;                  // 0..23

  int tid = threadIdx.x;
  int lane = tid & 63;
  int wr = (tid >> 6) >> 2;         // 0..1  (wave M row, 128 each)
  int wc = (tid >> 6) & 3;          // 0..3  (wave N col, 64 each)

  // A staging (R5): thread t covers rows (t>>2)+{0,128}, swizzled chunk
  int s_row = tid >> 2;                        // 0..127
  int s_q   = (tid & 3) ^ ((tid >> 3) & 3);    // chunk q ^ ((row>>1)&3)
  const unsigned short* Xg = Xb + ((size_t)bm * 256 + s_row) * K_DIM + s_q * 8;

  // A fragment read base (R5, conflict-free): row=lane&15 (+16/frag),
  // stored chunk (lane>>4)^((lane>>1)&3)
  int fr = lane & 15;
  int fq = (lane >> 4) ^ ((lane >> 1) & 3);
  const unsigned short* Ab = As + ((wr * 128 + fr) << 5) + (fq << 3);

  // B fragment-native base: panel bn, wave column wc, this lane's 16B
  const char* Wf = (const char*)Wb + (((size_t)bn * 96) << 14) + (wc << 12) + lane * 16;

#define STAGE_A(T, SLOT) {                                                      \
    const unsigned short* _xp = Xg + (size_t)(T) * 32;                          \
    unsigned short* _la = As + (SLOT) * 8192 + tid * 8;                         \
    gload16(_xp, _la);                                                          \
    gload16(_xp + (size_t)128 * K_DIM, _la + 4096); }

#define BLOAD(T, SET) {                                                         \
    const char* _wp = Wf + ((size_t)(T) << 14);                                 \
    SET[0] = *(const short8*)(_wp);                                             \
    SET[1] = *(const short8*)(_wp + 1024);                                      \
    SET[2] = *(const short8*)(_wp + 2048);                                      \
    SET[3] = *(const short8*)(_wp + 3072); }

  f32x4v acc[8][4];
#pragma unroll
  for (int m = 0; m < 8; ++m)
#pragma unroll
    for (int n = 0; n < 4; ++n) acc[m][n] = (f32x4v)0.0f;

  short8 bset0[4], bset1[4];

  // prologue order matters for vmcnt counting: A0, B0, A1, A2
  STAGE_A(0, 0);
  __builtin_amdgcn_sched_barrier(0);
  BLOAD(0, bset0);
  __builtin_amdgcn_sched_barrier(0);
  STAGE_A(1, 1);
  STAGE_A(2, 2);

  // BODY(t): vmcnt(8)+barrier (A(t) is >=13th-newest vmem op -> arrived;
  // slot (t+3)&3's readers [body t-1] passed this barrier); issue B(t+1)
  // into the spare set; stage A(t+3); 8 ds_read A-frags; 32 MFMA.
#define BODY(S, T, CONS, LOADSET, DOSTAGE, DOBLOAD) {                           \
    asm volatile("s_waitcnt vmcnt(8)\n\ts_barrier" ::: "memory");               \
    if (DOBLOAD) BLOAD((T) + 1, LOADSET);                                       \
    __builtin_amdgcn_sched_barrier(0);                                          \
    if (DOSTAGE) STAGE_A((T) + 3, ((S) + 3) & 3);                               \
    const unsigned short* _ab = Ab + (S) * 8192;                                \
    short8 a[8];                                                                \
    _Pragma("unroll") for (int m = 0; m < 8; ++m)                               \
      a[m] = *(const short8*)(_ab + m * 512);                                   \
    __builtin_amdgcn_s_setprio(1);                                              \
    _Pragma("unroll") for (int m = 0; m < 8; ++m)                               \
      _Pragma("unroll") for (int n = 0; n < 4; ++n)                             \
        acc[m][n] = __builtin_amdgcn_mfma_f32_16x16x32_bf16(a[m], CONS[n], acc[m][n], 0, 0, 0); \
    __builtin_amdgcn_s_setprio(0); }

  // bodies 0..3 (body0 same vmcnt(8): A0 has 8 newer ops in flight)
  BODY(0, 0, bset0, bset1, 1, 1);
  BODY(1, 1, bset1, bset0, 1, 1);
  BODY(2, 2, bset0, bset1, 1, 1);
  BODY(3, 3, bset1, bset0, 1, 1);
  for (int tt = 4; tt < 92; tt += 4) {   // t = 4..91, stages t+3 <= 94
    BODY(0, tt + 0, bset0, bset1, 1, 1);
    BODY(1, tt + 1, bset1, bset0, 1, 1);
    BODY(2, tt + 2, bset0, bset1, 1, 1);
    BODY(3, tt + 3, bset1, bset0, 1, 1);
  }
  BODY(0, 92, bset0, bset1, 1, 1);   // stages A95, loads B93
  BODY(1, 93, bset1, bset0, 0, 1);   // loads B94
  BODY(2, 94, bset0, bset1, 0, 1);   // loads B95
  BODY(3, 95, bset1, bset0, 0, 0);
#undef BODY
#undef BLOAD
#undef STAGE_A

  // C/D layout: ncol = lane&15, mrow = (lane>>4)*4 + reg
  int mrow0 = bm * 256 + wr * 128 + ((lane >> 4) << 2);
  int ncol0 = bn * 256 + wc * 64 + (lane & 15);
#pragma unroll
  for (int m = 0; m < 8; ++m)
#pragma unroll
    for (int n = 0; n < 4; ++n)
#pragma unroll
      for (int r = 0; r < 4; ++r)
        Y[(size_t)(mrow0 + m * 16 + r) * N_DIM + ncol0 + n * 16] = acc[m][n][r];
}

// ================= fallback (R1 kernel) if ws too small =================
#define BM 128
#define BN 128
#define NTN (N_DIM / BN)
#define NK2 (K_DIM / 64)
__global__ __launch_bounds__(256, 2) void dq_gemm(
    const float* __restrict__ X, const float* __restrict__ W,
    const float* __restrict__ S, float* __restrict__ Y) {
  __shared__ unsigned short As[BM * 64];
  __shared__ unsigned short Bs[BN * 64];
  int bid = blockIdx.x;
  int cpx = gridDim.x >> 3;
  int wg = (bid & 7) * cpx + (bid >> 3);
  int bm = wg / NTN, bn = wg - (wg / NTN) * NTN;
  int tid = threadIdx.x, lane = tid & 63, wave = tid >> 6;
  int wm = (wave >> 1) << 6, wn = (wave & 1) << 6;
  const float* Xg = X + (size_t)bm * BM * K_DIM;
  const float* Wg = W + (size_t)bn * BN * K_DIM;
  int r0 = tid >> 4, c4 = tid & 15;
  f32x4v acc[4][4];
#pragma unroll
  for (int i = 0; i < 4; ++i)
#pragma unroll
    for (int jj = 0; jj < 4; ++jj) acc[i][jj] = (f32x4v)0.0f;
  float4 xa[8], xb[8];
#pragma unroll
  for (int i = 0; i < 8; ++i) xa[i] = *(const float4*)(Xg + (size_t)(i * 16 + r0) * K_DIM + c4 * 4);
#pragma unroll
  for (int i = 0; i < 8; ++i) xb[i] = *(const float4*)(Wg + (size_t)(i * 16 + r0) * K_DIM + c4 * 4);
  char* Ac = (char*)As; char* Bc = (char*)Bs;
  int sw = (lane & 7) << 4, kb = (lane >> 4) << 4;
  int rA = wm + (lane & 15), rB = wn + (lane & 15);
  for (int kk = 0; kk < NK2; ++kk) {
    float s = S[bn * NBK + (kk >> 1)];
    __syncthreads();
#pragma unroll
    for (int i = 0; i < 8; ++i) {
      int row = i * 16 + r0;
      int off = row * 128 + ((c4 * 8) ^ ((row & 7) << 4));
      *(uint2*)(Ac + off) = make_uint2(pk2bf(xa[i].x, xa[i].y), pk2bf(xa[i].z, xa[i].w));
      *(uint2*)(Bc + off) = make_uint2(pk2bf(xb[i].x * s, xb[i].y * s), pk2bf(xb[i].z * s, xb[i].w * s));
    }
    __syncthreads();
    if (kk + 1 < NK2) {
      const float* Xn = Xg + (size_t)(kk + 1) * 64;
      const float* Wn = Wg + (size_t)(kk + 1) * 64;
#pragma unroll
      for (int i = 0; i < 8; ++i) xa[i] = *(const float4*)(Xn + (size_t)(i * 16 + r0) * K_DIM + c4 * 4);
#pragma unroll
      for (int i = 0; i < 8; ++i) xb[i] = *(const float4*)(Wn + (size_t)(i * 16 + r0) * K_DIM + c4 * 4);
    }
    short8 a0[4], a1[4], b0[4], b1[4];
#pragma unroll
    for (int i = 0; i < 4; ++i) {
      int rowA = rA + i * 16, rowB = rB + i * 16;
      a0[i] = *(const short8*)(Ac + rowA * 128 + (kb ^ sw));
      a1[i] = *(const short8*)(Ac + rowA * 128 + ((kb + 64) ^ sw));
      b0[i] = *(const short8*)(Bc + rowB * 128 + (kb ^ sw));
      b1[i] = *(const short8*)(Bc + rowB * 128 + ((kb + 64) ^ sw));
    }
#pragma unroll
    for (int i = 0; i < 4; ++i)
#pragma unroll
      for (int jj = 0; jj < 4; ++jj) {
        acc[i][jj] = __builtin_amdgcn_mfma_f32_16x16x32_bf16(a0[i], b0[jj], acc[i][jj], 0, 0, 0);
        acc[i][jj] = __builtin_amdgcn_mfma_f32_16x16x32_bf16(a1[i], b1[jj], acc[i][jj], 0, 0, 0);
      }
  }
  int mrow0 = bm * BM + wm + ((lane >> 4) << 2);
  int ncol0 = bn * BN + wn + (lane & 15);
#pragma unroll
  for (int i = 0; i < 4; ++i)
#pragma unroll
    for (int jj = 0; jj < 4; ++jj)
#pragma unroll
      for (int r = 0; r < 4; ++r)
        Y[(size_t)(mrow0 + i * 16 + r) * N_DIM + ncol0 + jj * 16] = acc[i][jj][r];
}

extern "C" void kernel_launch(void* const* d_in, const int* in_sizes, int n_in,
                              void* d_out, int out_size, void* d_ws, size_t ws_size,
                              hipStream_t stream) {
  const float* X = (const float*)d_in[0];
  const float* W = (const float*)d_in[1];
  const float* S = (const float*)d_in[2];
  float* Y = (float*)d_out;

  const size_t xb_bytes = (size_t)M_DIM * K_DIM * 2;
  const size_t wb_bytes = (size_t)N_DIM * K_DIM * 2;
  if (ws_size >= xb_bytes + wb_bytes) {
    unsigned short* Xbf = (unsigned short*)d_ws;
    unsigned short* Wbf = (unsigned short*)((char*)d_ws + xb_bytes);
    cvt_x<<<2048, 256, 0, stream>>>(X, (uint2*)Xbf, M_DIM * K_DIM / 4);
    cvt_w<<<2048, 256, 0, stream>>>(W, S, (uint4*)Wbf, N_DIM * K_DIM / 8);
    static int attr_set = 0;
    if (!attr_set) {
      hipFuncSetAttribute((const void*)gemm_breg,
                          hipFuncAttributeMaxDynamicSharedMemorySize, 65536);
      attr_set = 1;
    }
    dim3 grid((M_DIM / 256) * (N_DIM / 256));  // 768
    gemm_breg<<<grid, 512, 65536, stream>>>(Xbf, Wbf, Y);
  } else {
    dim3 grid((M_DIM / BM) * (N_DIM / BN));
    dq_gemm<<<grid, 256, 0, stream>>>(X, W, S, Y);
  }
}

// Round 12
// 328.620 us; speedup vs baseline: 1.1003x; 1.0923x over previous
//
#include <hip/hip_runtime.h>

#define M_DIM 8192
#define N_DIM 6144
#define K_DIM 3072
#define NKT 96            // K / 32 K-tiles
#define NBK (K_DIM / 128) // 24 scale blocks along K

typedef __attribute__((ext_vector_type(8))) short short8;
typedef __attribute__((ext_vector_type(4))) float f32x4v;

// round-to-nearest-even f32->bf16, two packed into a u32
__device__ __forceinline__ unsigned int pk2bf(float a, float b) {
  unsigned int ua = __float_as_uint(a);
  unsigned int ub = __float_as_uint(b);
  ua = (ua + 0x7FFFu + ((ua >> 16) & 1u)) >> 16;
  ub = (ub + 0x7FFFu + ((ub >> 16) & 1u)) & 0xFFFF0000u;
  return ua | ub;
}

__global__ void cvt_x(const float* __restrict__ X, uint2* __restrict__ O, int n4) {
  int stride = gridDim.x * blockDim.x;
  for (int i = blockIdx.x * blockDim.x + threadIdx.x; i < n4; i += stride) {
    float4 v = ((const float4*)X)[i];
    O[i] = make_uint2(pk2bf(v.x, v.y), pk2bf(v.z, v.w));
  }
}

__global__ void cvt_w(const float* __restrict__ W, const float* __restrict__ S,
                      uint2* __restrict__ O, int n4) {
  int stride = gridDim.x * blockDim.x;
  for (int i = blockIdx.x * blockDim.x + threadIdx.x; i < n4; i += stride) {
    unsigned int e = (unsigned int)i * 4u;
    unsigned int n = e / K_DIM;
    unsigned int k = e - n * K_DIM;
    float s = S[(n >> 7) * NBK + (k >> 7)];
    float4 v = ((const float4*)W)[i];
    O[i] = make_uint2(pk2bf(v.x * s, v.y * s), pk2bf(v.z * s, v.w * s));
  }
}

__device__ __forceinline__ void gload16(const unsigned short* g, unsigned short* l) {
  __builtin_amdgcn_global_load_lds(
      (const __attribute__((address_space(1))) void*)g,
      (__attribute__((address_space(3))) void*)l, 16, 0, 0);
}

// 256x256 tile, BK=32, ring-4 LDS slots (128 KB) — R5's proven schedule,
// plus B-FRAGMENT SOFTWARE PIPELINE: body t reads tile t+1's 4 B-frags
// BETWEEN the two MFMA half-clusters (under the MFMA shadow), consuming
// B-frags read one body earlier. vmcnt(4) (vs R5's 8) guarantees slot t+1
// is staged before its early B-read; slot-reuse audit: slot (t+1)&3's
// b-reads at body t complete before body t+2 overwrites it.
// LDS layout: row-major 64B rows, quad-local XOR swizzle (conflict-free):
// chunk q stored at q ^ ((row>>1)&3).
// NOTE: ~254 unified VGPR+AGPR/wave; launch_bounds min-waves MUST stay 2
// (R8: forcing 4 spilled acc -> 4 ms; watch WRITE_SIZE for spill).
__global__ __launch_bounds__(512, 2) void gemm_ring(
    const unsigned short* __restrict__ Xb, const unsigned short* __restrict__ Wb,
    float* __restrict__ Y) {
  extern __shared__ unsigned short lds[];   // As[4][8192] ++ Bs[4][8192] = 128 KB
  unsigned short* As = lds;
  unsigned short* Bs = lds + 32768;

  // XCD-aware mapping: 768 blocks = 8 XCD x 96; each XCD owns 4 bm-panels x 24 bn
  int bid = blockIdx.x;
  int c = bid & 7;
  int j = bid >> 3;                 // 0..95
  int bm = c * 4 + (j / 24);        // 0..31
  int bn = j % 24;                  // 0..23

  int tid = threadIdx.x;
  int lane = tid & 63;
  int wr = (tid >> 6) >> 2;         // 0..1  (wave M row)
  int wc = (tid >> 6) & 3;          // 0..3  (wave N col)

  // staging: thread t covers rows (t>>2)+{0,128}, 16B chunk ((t&3) ^ ((t>>3)&3))
  int s_row = tid >> 2;                        // 0..127
  int s_q   = (tid & 3) ^ ((tid >> 3) & 3);    // swizzled source chunk
  const unsigned short* Xg = Xb + ((size_t)bm * 256 + s_row) * K_DIM + s_q * 8;
  const unsigned short* Wg = Wb + ((size_t)bn * 256 + s_row) * K_DIM + s_q * 8;
  unsigned short* lax = As + tid * 8;       // linear LDS dest (uniform + lane*16B)
  unsigned short* lbx = Bs + tid * 8;

  // fragment read bases: row r = lane&15 (+16 per frag), chunk (lane>>4)^((lane>>1)&3)
  int fr = lane & 15;
  int fq = (lane >> 4) ^ ((lane >> 1) & 3);
  const unsigned short* Ab = As + ((wr * 128 + fr) << 5) + (fq << 3);
  const unsigned short* Bb = Bs + ((wc * 64 + fr) << 5) + (fq << 3);

#define STAGE(t) { int _sl = ((t) & 3) * 8192;                                  \
    const unsigned short* _xp = Xg + (size_t)(t) * 32;                          \
    const unsigned short* _wp = Wg + (size_t)(t) * 32;                          \
    gload16(_xp, lax + _sl);                                                    \
    gload16(_xp + (size_t)128 * K_DIM, lax + _sl + 4096);                       \
    gload16(_wp, lbx + _sl);                                                    \
    gload16(_wp + (size_t)128 * K_DIM, lbx + _sl + 4096); }

  f32x4v acc[8][4];
#pragma unroll
  for (int m = 0; m < 8; ++m)
#pragma unroll
    for (int n = 0; n < 4; ++n) acc[m][n] = (f32x4v)0.0f;

  short8 bA[4], bB[4];

  STAGE(0); STAGE(1); STAGE(2);   // 12 loads in flight
  asm volatile("s_waitcnt vmcnt(8)\n\ts_barrier" ::: "memory");  // slot 0 landed (all waves)
#pragma unroll
  for (int n = 0; n < 4; ++n)
    bA[n] = *(const short8*)(Bb + n * 512);   // B-frags for tile 0

  // BODY(t): vmcnt(VM)+barrier (VM=4: slots t AND t+1 staged; barrier:
  // stage-slot (t-1)&3's readers done); stage t+3; read 8 A-frags slot t;
  // MFMA m=0..3 with CONS; [sched_barrier] read NXT B-frags from slot t+1
  // (under MFMA shadow); MFMA m=4..7.
#define BODY(T, VM, DOSTAGE, DOBN, CONS, NXT) {                                 \
    asm volatile("s_waitcnt vmcnt(" #VM ")\n\ts_barrier" ::: "memory");         \
    if (DOSTAGE) STAGE((T) + 3);                                                \
    int sl = ((T) & 3) * 8192;                                                  \
    int sln = (((T) + 1) & 3) * 8192;                                           \
    short8 a[8];                                                                \
    _Pragma("unroll") for (int m = 0; m < 8; ++m)                               \
      a[m] = *(const short8*)(Ab + sl + m * 512);                               \
    __builtin_amdgcn_s_setprio(1);                                              \
    _Pragma("unroll") for (int m = 0; m < 4; ++m)                               \
      _Pragma("unroll") for (int n = 0; n < 4; ++n)                             \
        acc[m][n] = __builtin_amdgcn_mfma_f32_16x16x32_bf16(a[m], CONS[n], acc[m][n], 0, 0, 0); \
    __builtin_amdgcn_sched_barrier(0);                                          \
    if (DOBN) { _Pragma("unroll") for (int n = 0; n < 4; ++n)                   \
      NXT[n] = *(const short8*)(Bb + sln + n * 512); }                          \
    _Pragma("unroll") for (int m = 4; m < 8; ++m)                               \
      _Pragma("unroll") for (int n = 0; n < 4; ++n)                             \
        acc[m][n] = __builtin_amdgcn_mfma_f32_16x16x32_bf16(a[m], CONS[n], acc[m][n], 0, 0, 0); \
    __builtin_amdgcn_s_setprio(0); }

  for (int tt = 0; tt < 92; tt += 4) {   // t = 0..91, stages 3..94
    BODY(tt + 0, 4, 1, 1, bA, bB);
    BODY(tt + 1, 4, 1, 1, bB, bA);
    BODY(tt + 2, 4, 1, 1, bA, bB);
    BODY(tt + 3, 4, 1, 1, bB, bA);
  }
  BODY(92, 4, 1, 1, bA, bB);   // stages 95; reads b(93)
  BODY(93, 4, 0, 1, bB, bA);   // reads b(94)
  BODY(94, 0, 0, 1, bA, bB);   // vmcnt(0): slot 95 landed; reads b(95)
  BODY(95, 0, 0, 0, bB, bA);
#undef BODY
#undef STAGE

  // C/D layout: ncol = lane&15, mrow = (lane>>4)*4 + reg
  int mrow0 = bm * 256 + wr * 128 + ((lane >> 4) << 2);
  int ncol0 = bn * 256 + wc * 64 + (lane & 15);
#pragma unroll
  for (int m = 0; m < 8; ++m)
#pragma unroll
    for (int n = 0; n < 4; ++n)
#pragma unroll
      for (int r = 0; r < 4; ++r)
        Y[(size_t)(mrow0 + m * 16 + r) * N_DIM + ncol0 + n * 16] = acc[m][n][r];
}

// ================= fallback (R1 kernel) if ws too small =================
#define BM 128
#define BN 128
#define NTN (N_DIM / BN)
#define NK2 (K_DIM / 64)
__global__ __launch_bounds__(256, 2) void dq_gemm(
    const float* __restrict__ X, const float* __restrict__ W,
    const float* __restrict__ S, float* __restrict__ Y) {
  __shared__ unsigned short As[BM * 64];
  __shared__ unsigned short Bs[BN * 64];
  int bid = blockIdx.x;
  int cpx = gridDim.x >> 3;
  int wg = (bid & 7) * cpx + (bid >> 3);
  int bm = wg / NTN, bn = wg - (wg / NTN) * NTN;
  int tid = threadIdx.x, lane = tid & 63, wave = tid >> 6;
  int wm = (wave >> 1) << 6, wn = (wave & 1) << 6;
  const float* Xg = X + (size_t)bm * BM * K_DIM;
  const float* Wg = W + (size_t)bn * BN * K_DIM;
  int r0 = tid >> 4, c4 = tid & 15;
  f32x4v acc[4][4];
#pragma unroll
  for (int i = 0; i < 4; ++i)
#pragma unroll
    for (int jj = 0; jj < 4; ++jj) acc[i][jj] = (f32x4v)0.0f;
  float4 xa[8], xb[8];
#pragma unroll
  for (int i = 0; i < 8; ++i) xa[i] = *(const float4*)(Xg + (size_t)(i * 16 + r0) * K_DIM + c4 * 4);
#pragma unroll
  for (int i = 0; i < 8; ++i) xb[i] = *(const float4*)(Wg + (size_t)(i * 16 + r0) * K_DIM + c4 * 4);
  char* Ac = (char*)As; char* Bc = (char*)Bs;
  int sw = (lane & 7) << 4, kb = (lane >> 4) << 4;
  int rA = wm + (lane & 15), rB = wn + (lane & 15);
  for (int kk = 0; kk < NK2; ++kk) {
    float s = S[bn * NBK + (kk >> 1)];
    __syncthreads();
#pragma unroll
    for (int i = 0; i < 8; ++i) {
      int row = i * 16 + r0;
      int off = row * 128 + ((c4 * 8) ^ ((row & 7) << 4));
      *(uint2*)(Ac + off) = make_uint2(pk2bf(xa[i].x, xa[i].y), pk2bf(xa[i].z, xa[i].w));
      *(uint2*)(Bc + off) = make_uint2(pk2bf(xb[i].x * s, xb[i].y * s), pk2bf(xb[i].z * s, xb[i].w * s));
    }
    __syncthreads();
    if (kk + 1 < NK2) {
      const float* Xn = Xg + (size_t)(kk + 1) * 64;
      const float* Wn = Wg + (size_t)(kk + 1) * 64;
#pragma unroll
      for (int i = 0; i < 8; ++i) xa[i] = *(const float4*)(Xn + (size_t)(i * 16 + r0) * K_DIM + c4 * 4);
#pragma unroll
      for (int i = 0; i < 8; ++i) xb[i] = *(const float4*)(Wn + (size_t)(i * 16 + r0) * K_DIM + c4 * 4);
    }
    short8 a0[4], a1[4], b0[4], b1[4];
#pragma unroll
    for (int i = 0; i < 4; ++i) {
      int rowA = rA + i * 16, rowB = rB + i * 16;
      a0[i] = *(const short8*)(Ac + rowA * 128 + (kb ^ sw));
      a1[i] = *(const short8*)(Ac + rowA * 128 + ((kb + 64) ^ sw));
      b0[i] = *(const short8*)(Bc + rowB * 128 + (kb ^ sw));
      b1[i] = *(const short8*)(Bc + rowB * 128 + ((kb + 64) ^ sw));
    }
#pragma unroll
    for (int i = 0; i < 4; ++i)
#pragma unroll
      for (int jj = 0; jj < 4; ++jj) {
        acc[i][jj] = __builtin_amdgcn_mfma_f32_16x16x32_bf16(a0[i], b0[jj], acc[i][jj], 0, 0, 0);
        acc[i][jj] = __builtin_amdgcn_mfma_f32_16x16x32_bf16(a1[i], b1[jj], acc[i][jj], 0, 0, 0);
      }
  }
  int mrow0 = bm * BM + wm + ((lane >> 4) << 2);
  int ncol0 = bn * BN + wn + (lane & 15);
#pragma unroll
  for (int i = 0; i < 4; ++i)
#pragma unroll
    for (int jj = 0; jj < 4; ++jj)
#pragma unroll
      for (int r = 0; r < 4; ++r)
        Y[(size_t)(mrow0 + i * 16 + r) * N_DIM + ncol0 + jj * 16] = acc[i][jj][r];
}

extern "C" void kernel_launch(void* const* d_in, const int* in_sizes, int n_in,
                              void* d_out, int out_size, void* d_ws, size_t ws_size,
                              hipStream_t stream) {
  const float* X = (const float*)d_in[0];
  const float* W = (const float*)d_in[1];
  const float* S = (const float*)d_in[2];
  float* Y = (float*)d_out;

  const size_t xb_bytes = (size_t)M_DIM * K_DIM * 2;
  const size_t wb_bytes = (size_t)N_DIM * K_DIM * 2;
  if (ws_size >= xb_bytes + wb_bytes) {
    unsigned short* Xbf = (unsigned short*)d_ws;
    unsigned short* Wbf = (unsigned short*)((char*)d_ws + xb_bytes);
    cvt_x<<<2048, 256, 0, stream>>>(X, (uint2*)Xbf, M_DIM * K_DIM / 4);
    cvt_w<<<2048, 256, 0, stream>>>(W, S, (uint2*)Wbf, N_DIM * K_DIM / 4);
    static int attr_set = 0;
    if (!attr_set) {
      hipFuncSetAttribute((const void*)gemm_ring,
                          hipFuncAttributeMaxDynamicSharedMemorySize, 131072);
      attr_set = 1;
    }
    dim3 grid((M_DIM / 256) * (N_DIM / 256));  // 768
    gemm_ring<<<grid, 512, 131072, stream>>>(Xbf, Wbf, Y);
  } else {
    dim3 grid((M_DIM / BM) * (N_DIM / BN));
    dq_gemm<<<grid, 256, 0, stream>>>(X, W, S, Y);
  }
}